// Round 4
// baseline (3290.613 us; speedup 1.0000x reference)
//
#include <hip/hip_runtime.h>
#include <stdint.h>

#define DI __device__ __forceinline__

typedef __attribute__((ext_vector_type(8))) short short8;
typedef __attribute__((ext_vector_type(4))) float f32x4;

DI float bf2f(uint16_t u){ union{uint32_t i; float f;} v; v.i = ((uint32_t)u)<<16; return v.f; }
DI uint16_t f2bf(float f){
    union{float f; uint32_t i;} v; v.f = f;
    uint32_t r = v.i + 0x7FFFu + ((v.i>>16)&1u);
    return (uint16_t)(r>>16);
}
DI float sigm(float x){ return 1.f/(1.f+__expf(-x)); }
DI float tanhx(float x){ float e=__expf(-2.f*fabsf(x)); float t=(1.f-e)/(1.f+e); return x<0.f? -t : t; }
DI void unp2(uint32_t u, float&a, float&b){ a = bf2f((uint16_t)(u&0xFFFFu)); b = bf2f((uint16_t)(u>>16)); }

#define MFMA(a,b,c) __builtin_amdgcn_mfma_f32_16x16x32_bf16((a),(b),(c),0,0,0)

// T=256, N=1024, H=256, L=16, NL=32, C=64, NA=16

// -------------------------------------------------------------------------
// k_detect: decide whether float tensors are stored fp32 (flag=1) or bf16.
// -------------------------------------------------------------------------
__global__ void k_detect(const uint16_t* __restrict__ embed, int* __restrict__ flag){
  __shared__ int bad;
  if (threadIdx.x == 0) bad = 0;
  __syncthreads();
  float v = bf2f(embed[threadIdx.x]);
  if (!(fabsf(v) <= 100.f)) atomicAdd(&bad, 1);
  __syncthreads();
  if (threadIdx.x == 0) flag[0] = (bad > 0) ? 1 : 0;
}

struct CvtEnt { const void* src; uint16_t* dst; int n; int pad; };
struct CvtTab { CvtEnt e[26]; };

__global__ __launch_bounds__(1024) void k_convert_small(CvtTab tab, const int* __restrict__ flag){
  CvtEnt E = tab.e[blockIdx.x];
  if (flag[0]){
    const float* s = (const float*)E.src;
    for (int i = threadIdx.x; i < E.n; i += 1024) E.dst[i] = f2bf(s[i]);
  } else {
    const uint16_t* s = (const uint16_t*)E.src;
    for (int i = threadIdx.x; i < E.n; i += 1024) E.dst[i] = s[i];
  }
}

__global__ __launch_bounds__(256) void k_convert_big(const void* __restrict__ src,
                                                     uint16_t* __restrict__ dst,
                                                     int n8, const int* __restrict__ flag){
  int i = blockIdx.x*256 + threadIdx.x;    // each handles 8 elements
  if (i >= n8) return;
  if (flag[0]){
    const float4* s = (const float4*)src;
    float4 a = s[(size_t)i*2], b = s[(size_t)i*2+1];
    union { uint16_t u[8]; uint4 v; } o;
    o.u[0]=f2bf(a.x); o.u[1]=f2bf(a.y); o.u[2]=f2bf(a.z); o.u[3]=f2bf(a.w);
    o.u[4]=f2bf(b.x); o.u[5]=f2bf(b.y); o.u[6]=f2bf(b.z); o.u[7]=f2bf(b.w);
    *(uint4*)&dst[(size_t)i*8] = o.v;
  } else {
    *(uint4*)&dst[(size_t)i*8] = ((const uint4*)src)[i];
  }
}

// -------------------------------------------------------------------------
// k_tables: GiE[dir][e][768] = embed[e] @ wih_dir.T + bih_dir   (fp32 out)
// -------------------------------------------------------------------------
__global__ __launch_bounds__(256) void k_tables(
    const uint16_t* __restrict__ embed,
    const uint16_t* __restrict__ wih_f, const uint16_t* __restrict__ bih_f,
    const uint16_t* __restrict__ wih_b, const uint16_t* __restrict__ bih_b,
    float* __restrict__ GiE)
{
  int dir = blockIdx.x >> 5, e = blockIdx.x & 31;
  const uint16_t* wih = dir ? wih_b : wih_f;
  const uint16_t* bih = dir ? bih_b : bih_f;
  __shared__ float emb[256];
  int tid = threadIdx.x;
  emb[tid] = bf2f(embed[e*256 + tid]);
  __syncthreads();
  for (int c = tid; c < 768; c += 256){
    float s = bf2f(bih[c]);
    const uint32_t* wr = (const uint32_t*)(wih + (size_t)c*256);
    #pragma unroll 4
    for (int k2 = 0; k2 < 128; ++k2){
      float a, b; unp2(wr[k2], a, b);
      s += emb[k2*2]*a + emb[k2*2+1]*b;
    }
    GiE[(size_t)(dir*32 + e)*768 + c] = s;
  }
}

// -------------------------------------------------------------------------
// k_encoder: persistent bidirectional GRU over all 16 cyclic rolls.
// -------------------------------------------------------------------------
__global__ __launch_bounds__(512,2) void k_encoder(
    const int* __restrict__ lines, const float* __restrict__ GiE,
    const uint16_t* __restrict__ whh_f, const uint16_t* __restrict__ whh_b,
    const uint16_t* __restrict__ bhh_f, const uint16_t* __restrict__ bhh_b,
    uint16_t* __restrict__ Hmem /* [16][1024][512] */)
{
  int b = blockIdx.x;
  int dir = b >> 8; b &= 255;
  int r = b >> 4, n0 = (b & 15) << 6;
  const uint16_t* whh = dir ? whh_b : whh_f;
  const uint16_t* bhh = dir ? bhh_b : bhh_f;
  const float* gte = GiE + (size_t)dir * (32*768);

  __shared__ uint16_t hbuf[64*264];
  __shared__ int lid_s[64*16];

  int tid = threadIdx.x;
  for (int s = tid; s < 1024; s += 512) lid_s[s] = lines[(n0 + (s>>4))*16 + (s&15)];
  for (int s = tid; s < 8448; s += 512) ((uint32_t*)hbuf)[s] = 0u;

  int w = tid >> 6, lane = tid & 63, l15 = lane & 15, q = lane >> 4;
  int cw = w << 5;
  int nc[6];
  nc[0]=cw; nc[1]=cw+16; nc[2]=256+cw; nc[3]=256+cw+16; nc[4]=512+cw; nc[5]=512+cw+16;
  float bh[6];
  #pragma unroll
  for (int i=0;i<6;i++) bh[i] = bf2f(bhh[nc[i]+l15]);

  float hreg[4][2][4];
  #pragma unroll
  for (int a=0;a<4;a++)
    #pragma unroll
    for (int c=0;c<2;c++)
      #pragma unroll
      for (int e=0;e<4;e++) hreg[a][c][e]=0.f;

  __syncthreads();

  for (int j=0;j<16;++j){
    int jj = dir ? (15-j) : j;
    int pos = (r + jj) & 15;
    f32x4 acc[4][6];
    #pragma unroll
    for (int mt=0;mt<4;mt++)
      #pragma unroll
      for (int u=0;u<6;u++) acc[mt][u] = (f32x4){0.f,0.f,0.f,0.f};
    #pragma unroll
    for (int kb=0;kb<8;kb++){
      short8 af[4];
      #pragma unroll
      for (int mt=0;mt<4;mt++)
        af[mt] = *(const short8*)&hbuf[(mt*16+l15)*264 + kb*32 + q*8];
      #pragma unroll
      for (int u=0;u<6;u++){
        short8 bf = *(const short8*)&whh[(size_t)(nc[u]+l15)*256 + kb*32 + q*8];
        #pragma unroll
        for (int mt=0;mt<4;mt++) acc[mt][u] = MFMA(af[mt], bf, acc[mt][u]);
      }
    }
    __syncthreads();
    #pragma unroll
    for (int mt=0;mt<4;mt++){
      int lidv[4];
      #pragma unroll
      for (int e=0;e<4;e++) lidv[e] = lid_s[(mt*16 + q*4 + e)*16 + pos];
      float gv[4][6];
      #pragma unroll
      for (int e=0;e<4;e++)
        #pragma unroll
        for (int u=0;u<6;u++) gv[e][u] = gte[(size_t)lidv[e]*768 + nc[u] + l15];
      #pragma unroll
      for (int c=0;c<2;c++)
        #pragma unroll
        for (int e=0;e<4;e++){
          float ghr = acc[mt][c  ][e] + bh[c  ];
          float ghz = acc[mt][2+c][e] + bh[2+c];
          float ghn = acc[mt][4+c][e] + bh[4+c];
          float rr = sigm(gv[e][c] + ghr);
          float zz = sigm(gv[e][2+c] + ghz);
          float nn = tanhx(gv[e][4+c] + rr*ghn);
          float hn = (1.f-zz)*nn + zz*hreg[mt][c][e];
          hreg[mt][c][e] = hn;
          hbuf[(mt*16 + q*4 + e)*264 + cw + c*16 + l15] = f2bf(hn);
        }
    }
    __syncthreads();
  }
  for (int s = tid; s < 8192; s += 512){
    int row = s >> 7, cp = (s & 127) << 1;
    uint32_t v = *(uint32_t*)&hbuf[row*264 + cp];
    *(uint32_t*)&Hmem[(size_t)((r<<10) + n0 + row)*512 + (dir<<8) + cp] = v;
  }
}

// -------------------------------------------------------------------------
// k_gemm: C[M,N](bf16) = act( A[M,K] @ W[N,K]^T + bias + gather )
// flags: 1=relu, 2=bias, 4=gather (G[(gidx[row]*1024 + row%1024)*256 + col])
//        8=phasec-swizzled output layout:
//          G'[t][nblk][w'][l15][q][u*4+e], u = (col>>8)*2 + ((col>>4)&1)
//          (so each k_phasec thread reads its 24 gate values as 48
//           contiguous bytes -> 3 dwordx4 loads instead of 24 scalars)
// -------------------------------------------------------------------------
__global__ __launch_bounds__(256,3) void k_gemm(
    const uint16_t* __restrict__ A, int lda,
    const uint16_t* __restrict__ W, int ldw, int woff,
    const uint16_t* __restrict__ bias,
    const int* __restrict__ gidx, const uint16_t* __restrict__ G,
    uint16_t* __restrict__ C, int ldc, int K, int flags)
{
  int n0 = blockIdx.x << 6, m0 = blockIdx.y << 7;
  int tid = threadIdx.x, w = tid>>6, lane = tid&63, l15 = lane&15, q = lane>>4;
  __shared__ uint16_t As[128*56];
  __shared__ uint16_t Ws[64*56];
  f32x4 acc[2][4];
  #pragma unroll
  for (int mt=0;mt<2;mt++)
    #pragma unroll
    for (int nt=0;nt<4;nt++) acc[mt][nt]=(f32x4){0.f,0.f,0.f,0.f};
  int nk = K >> 5;
  int arow0 = tid >> 2, ach = (tid & 3) << 3;
  for (int kb = 0; kb < nk; ++kb){
    int k0 = kb << 5;
    *(uint4*)&As[arow0*56 + ach]      = *(const uint4*)&A[(size_t)(m0+arow0)*lda + k0 + ach];
    *(uint4*)&As[(arow0+64)*56 + ach] = *(const uint4*)&A[(size_t)(m0+arow0+64)*lda + k0 + ach];
    *(uint4*)&Ws[arow0*56 + ach]      = *(const uint4*)&W[(size_t)(n0+arow0)*ldw + woff + k0 + ach];
    __syncthreads();
    short8 af[2], bfr[4];
    #pragma unroll
    for (int mt=0;mt<2;mt++) af[mt] = *(const short8*)&As[(w*32 + mt*16 + l15)*56 + q*8];
    #pragma unroll
    for (int nt=0;nt<4;nt++) bfr[nt] = *(const short8*)&Ws[(nt*16 + l15)*56 + q*8];
    #pragma unroll
    for (int mt=0;mt<2;mt++)
      #pragma unroll
      for (int nt=0;nt<4;nt++) acc[mt][nt] = MFMA(af[mt], bfr[nt], acc[mt][nt]);
    __syncthreads();
  }
  float bv[4] = {0.f,0.f,0.f,0.f};
  if (flags & 2){
    #pragma unroll
    for (int nt=0;nt<4;nt++) bv[nt] = bf2f(bias[n0 + nt*16 + l15]);
  }
  if (flags & 8){
    // phasec-swizzled store: pack 4 row-consecutive values into one 8B store
    #pragma unroll
    for (int mt=0;mt<2;mt++)
      #pragma unroll
      for (int nt=0;nt<4;nt++){
        int row0 = m0 + w*32 + mt*16 + q*4;       // rows row0..row0+3 (e fast)
        int t = row0 >> 10, n = row0 & 1023;
        int nblk = n >> 4;
        int colv = n0 + nt*16 + l15;
        int wp = (colv >> 5) & 7, u = (colv >> 8)*2 + ((colv >> 4) & 1);
        size_t base = ((((size_t)t*64 + nblk)*8 + wp)*16 + (size_t)l15)*96
                      + (size_t)q*24 + (size_t)u*4;
        union { uint16_t us[4]; uint2 v; } o;
        #pragma unroll
        for (int e=0;e<4;e++) o.us[e] = f2bf(acc[mt][nt][e] + bv[nt]);
        *(uint2*)&C[base] = o.v;
      }
  } else {
    #pragma unroll
    for (int mt=0;mt<2;mt++)
      #pragma unroll
      for (int e=0;e<4;e++){
        int row = m0 + w*32 + mt*16 + q*4 + e;
        size_t gb = 0;
        if (flags & 4) gb = ((size_t)gidx[row]*1024 + (size_t)(row & 1023))*256;
        #pragma unroll
        for (int nt=0;nt<4;nt++){
          int col = n0 + nt*16 + l15;
          float v = acc[mt][nt][e] + bv[nt];
          if (flags & 4) v += bf2f(G[gb + col]);
          if (flags & 1) v = fmaxf(v, 0.f);
          C[(size_t)row*ldc + col] = f2bf(v);
        }
      }
  }
}

// -------------------------------------------------------------------------
// k_phasec: sequential recurrence over a chunk of Tc steps.
// v4: kill the serialized Gi gather (the ~21k cy/step term).
//   * Gi is consumed in the flag-8 swizzled layout: each thread's 24 gate
//     values = 48 contiguous bytes -> 3 short8 loads (was 24 scalar ushort
//     loads that serialized at HBM latency under register pressure).
//   * Issue order per step: [weight batches (pipelined) + MFMAs] ->
//     [Gi prefetch (3 wide loads)] -> [deferred h_s store] -> [elementwise]
//     -> [barrier]. Weight vmcnt waits never have older HBM loads/stores
//     in front of them (in-order vmcnt retirement).
//   * double-buffered h tile, ONE __syncthreads per step (round-3 proven).
// -------------------------------------------------------------------------
__global__ __launch_bounds__(512,2) void k_phasec(
    const uint16_t* __restrict__ Gi, const uint16_t* __restrict__ c_whh,
    const uint16_t* __restrict__ c_bhh, const uint16_t* __restrict__ hinit,
    uint16_t* __restrict__ hcur, uint16_t* __restrict__ h_s, int Tc)
{
  int bx = blockIdx.x;
  int n0 = bx << 4;
  int tid = threadIdx.x, w = tid>>6, lane = tid&63, l15 = lane&15, q = lane>>4;
  int cw = w<<5;
  int nc[6];
  nc[0]=cw; nc[1]=cw+16; nc[2]=256+cw; nc[3]=256+cw+16; nc[4]=512+cw; nc[5]=512+cw+16;

  __shared__ uint16_t hb[2][16*264];   // double-buffered h tile (padded rows)

  // per-thread Gi base (swizzled layout), step stride = 64*8*16*96 = 786432 ushorts... 
  // offset(t) = ((((t*64+bx)*8+w)*16+l15)*96 + q*24
  const size_t gstep = (size_t)64*8*16*96;             // = 786432 = 1024*768
  size_t goff0 = (((size_t)bx*8 + w)*16 + (size_t)l15)*96 + (size_t)q*24;

  // ---- prologue ----
  for (int s = tid; s < 2048; s += 512){
    int row = s >> 7, cp = (s&127) << 1;
    uint32_t v = *(const uint32_t*)&hinit[(size_t)(n0+row)*256 + cp];
    *(uint32_t*)&hb[0][row*264 + cp] = v;
  }
  float bh[6];
  #pragma unroll
  for (int i=0;i<6;i++) bh[i] = bf2f(c_bhh[nc[i]+l15]);
  float hreg[2][4];
  #pragma unroll
  for (int c=0;c<2;c++)
    #pragma unroll
    for (int e=0;e<4;e++)
      hreg[c][e] = bf2f(hinit[(size_t)(n0+q*4+e)*256 + cw + c*16 + l15]);
  short8 gpk[3];
  {
    const uint16_t* gb = Gi + goff0;
    gpk[0] = *(const short8*)&gb[0];
    gpk[1] = *(const short8*)&gb[8];
    gpk[2] = *(const short8*)&gb[16];
  }
  __syncthreads();

  // unpack helper: value for (u,e) is element u*4+e of the packed 24
#define GV(u,e) bf2f((uint16_t)gpk[((u)*4+(e))>>3][((u)*4+(e))&7])

  int p = 0;
  for (int t=0;t<Tc;++t){
    // A: hh-matmul, weights streamed from L2 with 1-deep pipeline
    f32x4 acc[6];
    #pragma unroll
    for (int u=0;u<6;u++) acc[u] = (f32x4){0.f,0.f,0.f,0.f};
    short8 bf0[6], bf1[6];
    #pragma unroll
    for (int u=0;u<6;u++)
      bf0[u] = *(const short8*)&c_whh[(size_t)(nc[u]+l15)*256 + q*8];
    #pragma unroll
    for (int kb=0;kb<8;kb++){
      short8 af = *(const short8*)&hb[p][l15*264 + kb*32 + q*8];
      if (kb < 7){
        #pragma unroll
        for (int u=0;u<6;u++)
          ((kb&1)?bf0:bf1)[u] =
            *(const short8*)&c_whh[(size_t)(nc[u]+l15)*256 + (kb+1)*32 + q*8];
      }
      #pragma unroll
      for (int u=0;u<6;u++)
        acc[u] = MFMA(af, ((kb&1)?bf1:bf0)[u], acc[u]);
    }
    // B: Gi prefetch for t+1 (3 wide loads; issued AFTER all weight loads
    //    so no weight vmcnt wait is forced to drain them; barrier covers)
    short8 gn0, gn1, gn2;
    {
      int tn = (t+1 < Tc) ? (t+1) : t;
      const uint16_t* gb = Gi + (size_t)tn*gstep + goff0;
      gn0 = *(const short8*)&gb[0];
      gn1 = *(const short8*)&gb[8];
      gn2 = *(const short8*)&gb[16];
    }
    // C: deferred h_s store of h_{t-1} from hb[p] (still intact; acks
    //    retire during elementwise instead of inside a pre-matmul stall)
    if (t > 0){
      #pragma unroll
      for (int i=0;i<4;i++){
        int s = tid + i*512;
        int row = s >> 7, cp = (s&127) << 1;
        *(uint32_t*)&h_s[(size_t)(((t-1)<<10) + n0 + row)*256 + cp] =
            *(const uint32_t*)&hb[p][row*264 + cp];
      }
    }
    // D: elementwise GRU update using gpk (loaded last step)
    #pragma unroll
    for (int c=0;c<2;c++)
      #pragma unroll
      for (int e=0;e<4;e++){
        int row = q*4+e;
        float ghr = acc[c  ][e]+bh[c  ];
        float ghz = acc[2+c][e]+bh[2+c];
        float ghn = acc[4+c][e]+bh[4+c];
        float rr = sigm(GV(c,e)+ghr), zz = sigm(GV(2+c,e)+ghz);
        float nn = tanhx(GV(4+c,e) + rr*ghn);
        float hn = (1.f-zz)*nn + zz*hreg[c][e];
        hreg[c][e] = hn;
        hb[p^1][row*264 + cw + c*16 + l15] = f2bf(hn);
      }
    // E: single per-step barrier; rotate
    __syncthreads();
    gpk[0] = gn0; gpk[1] = gn1; gpk[2] = gn2;
    p ^= 1;
  }
#undef GV
  // epilogue: final tile -> hcur and h_s[Tc-1]
  for (int s = tid; s < 2048; s += 512){
    int row = s >> 7, cp = (s&127) << 1;
    uint32_t v = *(uint32_t*)&hb[p][row*264 + cp];
    *(uint32_t*)&hcur[(size_t)(n0+row)*256 + cp] = v;
    *(uint32_t*)&h_s[(size_t)(((Tc-1)<<10) + n0 + row)*256 + cp] = v;
  }
}

// -------------------------------------------------------------------------
// k_phased: heads + packing for one chunk. Output dtype chosen by flag.
// out row = 278: [a, p0, w, v, h(256), probs(16), pp0(2)]
// -------------------------------------------------------------------------
__global__ __launch_bounds__(256) void k_phased(
    const uint16_t* __restrict__ h_s /* chunk-local */,
    const uint16_t* __restrict__ w_actor, const uint16_t* __restrict__ b_actor,
    const uint16_t* __restrict__ w_critic, const uint16_t* __restrict__ b_critic,
    const int* __restrict__ actions /* global */, const int* __restrict__ active,
    const uint16_t* __restrict__ p0, const uint16_t* __restrict__ pp0,
    void* __restrict__ out, const int* __restrict__ flag, int row0g)
{
  int r0 = blockIdx.x << 6;          // chunk-local row base
  __shared__ uint16_t hb[64*264];
  __shared__ uint16_t wa[17*256];
  __shared__ float lv[64*18];
  int tid = threadIdx.x;
  for (int s = tid; s < 2048; s += 256){
    int row = s >> 5, ch = (s & 31) << 3;
    *(uint4*)&hb[row*264 + ch] = *(const uint4*)&h_s[(size_t)(r0+row)*256 + ch];
  }
  for (int s = tid; s < 512; s += 256)
    *(uint4*)&wa[s*8] = *(const uint4*)&w_actor[s*8];
  if (tid < 32) *(uint4*)&wa[4096 + tid*8] = *(const uint4*)&w_critic[tid*8];
  __syncthreads();
  int row = tid & 63, cg = tid >> 6;
  for (int c = cg; c < 17; c += 4){
    const uint32_t* hr = (const uint32_t*)&hb[row*264];
    const uint32_t* wr = (const uint32_t*)&wa[c*256];
    float s = 0.f;
    #pragma unroll 4
    for (int k2=0;k2<128;k2++){
      float a,b,c2,d; unp2(hr[k2],a,b); unp2(wr[k2],c2,d);
      s += a*c2 + b*d;
    }
    s += (c<16) ? bf2f(b_actor[c]) : bf2f(b_critic[0]);
    lv[row*18 + c] = s;
  }
  __syncthreads();
  if (tid < 64){
    float mx = -1e30f;
    #pragma unroll
    for (int c=0;c<16;c++) mx = fmaxf(mx, lv[tid*18+c]);
    float sum = 0.f;
    #pragma unroll
    for (int c=0;c<16;c++){ float ev = __expf(lv[tid*18+c]-mx); lv[tid*18+c]=ev; sum+=ev; }
    float inv = 1.f/sum;
    #pragma unroll
    for (int c=0;c<16;c++) lv[tid*18+c] *= inv;
  }
  __syncthreads();
  int isf = flag[0];
  float* outf = (float*)out;
  uint16_t* outb = (uint16_t*)out;
  for (int s = tid; s < 64*278; s += 256){
    int rw = s / 278, c = s - rw*278;
    int gr = row0g + r0 + rw;        // global row (t*1024+n)
    int n  = (r0 + rw) & 1023;
    float fv;
    if (c >= 4 && c < 260)        fv = bf2f(hb[rw*264 + (c-4)]);
    else if (c >= 260 && c < 276) fv = lv[rw*18 + (c-260)];
    else if (c == 0)              fv = (float)actions[gr];
    else if (c == 1)              fv = bf2f(p0[n]);
    else if (c == 2)              fv = (float)active[gr];
    else if (c == 3)              fv = lv[rw*18+16];
    else                          fv = bf2f(pp0[(n<<1) + (c-276)]);
    size_t off = (size_t)gr*278 + c;
    if (isf) outf[off] = fv;
    else     outb[off] = f2bf(fv);
  }
}

// -------------------------------------------------------------------------
extern "C" void kernel_launch(void* const* d_in, const int* in_sizes, int n_in,
                              void* d_out, int out_size, void* d_ws, size_t ws_size,
                              hipStream_t stream)
{
  (void)in_sizes; (void)n_in; (void)out_size;
  const int* active  = (const int*)d_in[1];
  const int* lines   = (const int*)d_in[2];
  const int* actions = (const int*)d_in[3];

  char* wsb = (char*)d_ws;
  size_t off = 0;
  auto aln  = [](size_t x){ return (x + 255) & ~(size_t)255; };
  auto carve = [&](size_t bytes)->char*{ char* p = wsb + off; off += aln(bytes); return p; };

  int*      flag   = (int*)     carve(256);
  float*    GiE    = (float*)   carve((size_t)2*32*768*4);
  uint16_t* Hmem   = (uint16_t*)carve((size_t)16*1024*512*2);
  uint16_t* Rpart  = (uint16_t*)carve((size_t)16384*256*2);
  uint16_t* hcur   = (uint16_t*)carve((size_t)1024*256*2);
  uint16_t* condbf = (uint16_t*)carve((size_t)262144*64*2);

  // bf16 copies of all float inputs
  struct Item { int idx; int n; };
  const Item items[26] = {
    {8,196608},{9,196608},{10,768},{11,768},{12,196608},{13,196608},{14,768},{15,768},
    {16,147456},{17,256},{18,65536},{19,256},{20,65536},{21,256},
    {22,196608},{23,196608},{24,768},{25,768},
    {26,256},{27,1},{28,4096},{29,16},{5,1024},{6,2048},{7,8192},{4,262144}};
  uint16_t* bf[30] = {};
  CvtTab tab;
  for (int i=0;i<26;i++){
    uint16_t* d = (uint16_t*)carve((size_t)items[i].n*2);
    bf[items[i].idx] = d;
    tab.e[i].src = d_in[items[i].idx];
    tab.e[i].dst = d;
    tab.e[i].n   = items[i].n;
    tab.e[i].pad = 0;
  }

  // pick chunk size from remaining workspace
  size_t fixedBytes = off;
  int Tc = 4;
  const int cands[7] = {256,128,64,32,16,8,4};
  for (int i=0;i<7;i++){
    int c = cands[i];
    size_t need = fixedBytes + 2*aln((size_t)c*1024*256*2) + aln((size_t)c*1024*768*2);
    if (need <= ws_size){ Tc = c; break; }
  }
  uint16_t* Xa  = (uint16_t*)carve((size_t)Tc*1024*256*2);
  uint16_t* Xb  = (uint16_t*)carve((size_t)Tc*1024*256*2);
  uint16_t* Gic = (uint16_t*)carve((size_t)Tc*1024*768*2);

  // 0) dtype detect + normalize to internal bf16
  k_detect<<<1,256,0,stream>>>((const uint16_t*)d_in[7], flag);
  k_convert_small<<<26,1024,0,stream>>>(tab, flag);
  k_convert_big<<<8192,256,0,stream>>>(d_in[0], condbf, 2097152, flag);

  // 1) input-side GRU tables
  k_tables<<<64,256,0,stream>>>(bf[7], bf[8], bf[10], bf[12], bf[14], GiE);
  // 2) bidirectional encoder -> Hmem [16][1024][512]
  k_encoder<<<512,512,0,stream>>>(lines, GiE, bf[9], bf[13], bf[11], bf[15], Hmem);
  // 3) Rpart = Hmem @ f_w0[:,64:].T
  k_gemm<<<dim3(4,128),256,0,stream>>>(Hmem,512, bf[16],576,64, nullptr, nullptr,nullptr,
                                       Rpart,256, 512, 0);
  // chunked T loop
  for (int t0 = 0; t0 < 256; t0 += Tc){
    const uint16_t* condc = condbf + (size_t)t0*1024*64;
    const int* activec = active + t0*1024;
    // X0 = relu(cond @ f_w0[:,:64].T + Rpart[active] + b0)
    k_gemm<<<dim3(4,Tc*8),256,0,stream>>>(condc,64, bf[16],576,0, bf[17], activec, Rpart,
                                          Xa,256, 64, 7);
    // X1 = relu(X0 @ f_w1.T + b1)
    k_gemm<<<dim3(4,Tc*8),256,0,stream>>>(Xa,256, bf[18],256,0, bf[19], nullptr,nullptr,
                                          Xb,256, 256, 3);
    // X2 = relu(X1 @ f_w2.T + b2)
    k_gemm<<<dim3(4,Tc*8),256,0,stream>>>(Xb,256, bf[20],256,0, bf[21], nullptr,nullptr,
                                          Xa,256, 256, 3);
    // Gi = X2 @ c_wih.T + c_bih   (flag 8: phasec-swizzled layout)
    k_gemm<<<dim3(12,Tc*8),256,0,stream>>>(Xa,256, bf[22],256,0, bf[24], nullptr,nullptr,
                                           Gic,768, 256, 10);
    // recurrence chunk (h_s into Xb; X1 is dead by now)
    k_phasec<<<64,512,0,stream>>>(Gic, bf[23], bf[25], (t0==0 ? bf[4] : hcur), hcur, Xb, Tc);
    // heads + packing
    k_phased<<<Tc*16,256,0,stream>>>(Xb, bf[28], bf[29], bf[26], bf[27],
                                     actions, active, bf[5], bf[6],
                                     d_out, flag, t0*1024);
  }
}

// Round 5
// 2932.685 us; speedup vs baseline: 1.1220x; 1.1220x over previous
//
#include <hip/hip_runtime.h>
#include <stdint.h>

#define DI __device__ __forceinline__

typedef __attribute__((ext_vector_type(8))) short short8;
typedef __attribute__((ext_vector_type(4))) float f32x4;

DI float bf2f(uint16_t u){ union{uint32_t i; float f;} v; v.i = ((uint32_t)u)<<16; return v.f; }
DI uint16_t f2bf(float f){
    union{float f; uint32_t i;} v; v.f = f;
    uint32_t r = v.i + 0x7FFFu + ((v.i>>16)&1u);
    return (uint16_t)(r>>16);
}
DI float sigm(float x){ return 1.f/(1.f+__expf(-x)); }
DI float tanhx(float x){ float e=__expf(-2.f*fabsf(x)); float t=(1.f-e)/(1.f+e); return x<0.f? -t : t; }
DI void unp2(uint32_t u, float&a, float&b){ a = bf2f((uint16_t)(u&0xFFFFu)); b = bf2f((uint16_t)(u>>16)); }

#define MFMA(a,b,c) __builtin_amdgcn_mfma_f32_16x16x32_bf16((a),(b),(c),0,0,0)

// T=256, N=1024, H=256, L=16, NL=32, C=64, NA=16

// -------------------------------------------------------------------------
// k_detect: decide whether float tensors are stored fp32 (flag=1) or bf16.
// -------------------------------------------------------------------------
__global__ void k_detect(const uint16_t* __restrict__ embed, int* __restrict__ flag){
  __shared__ int bad;
  if (threadIdx.x == 0) bad = 0;
  __syncthreads();
  float v = bf2f(embed[threadIdx.x]);
  if (!(fabsf(v) <= 100.f)) atomicAdd(&bad, 1);
  __syncthreads();
  if (threadIdx.x == 0) flag[0] = (bad > 0) ? 1 : 0;
}

struct CvtEnt { const void* src; uint16_t* dst; int n; int pad; };
struct CvtTab { CvtEnt e[26]; };

__global__ __launch_bounds__(1024) void k_convert_small(CvtTab tab, const int* __restrict__ flag){
  CvtEnt E = tab.e[blockIdx.x];
  if (flag[0]){
    const float* s = (const float*)E.src;
    for (int i = threadIdx.x; i < E.n; i += 1024) E.dst[i] = f2bf(s[i]);
  } else {
    const uint16_t* s = (const uint16_t*)E.src;
    for (int i = threadIdx.x; i < E.n; i += 1024) E.dst[i] = s[i];
  }
}

__global__ __launch_bounds__(256) void k_convert_big(const void* __restrict__ src,
                                                     uint16_t* __restrict__ dst,
                                                     int n8, const int* __restrict__ flag){
  int i = blockIdx.x*256 + threadIdx.x;    // each handles 8 elements
  if (i >= n8) return;
  if (flag[0]){
    const float4* s = (const float4*)src;
    float4 a = s[(size_t)i*2], b = s[(size_t)i*2+1];
    union { uint16_t u[8]; uint4 v; } o;
    o.u[0]=f2bf(a.x); o.u[1]=f2bf(a.y); o.u[2]=f2bf(a.z); o.u[3]=f2bf(a.w);
    o.u[4]=f2bf(b.x); o.u[5]=f2bf(b.y); o.u[6]=f2bf(b.z); o.u[7]=f2bf(b.w);
    *(uint4*)&dst[(size_t)i*8] = o.v;
  } else {
    *(uint4*)&dst[(size_t)i*8] = ((const uint4*)src)[i];
  }
}

// -------------------------------------------------------------------------
// k_tables: GiE[dir][e][768] = embed[e] @ wih_dir.T + bih_dir   (fp32 out)
// -------------------------------------------------------------------------
__global__ __launch_bounds__(256) void k_tables(
    const uint16_t* __restrict__ embed,
    const uint16_t* __restrict__ wih_f, const uint16_t* __restrict__ bih_f,
    const uint16_t* __restrict__ wih_b, const uint16_t* __restrict__ bih_b,
    float* __restrict__ GiE)
{
  int dir = blockIdx.x >> 5, e = blockIdx.x & 31;
  const uint16_t* wih = dir ? wih_b : wih_f;
  const uint16_t* bih = dir ? bih_b : bih_f;
  __shared__ float emb[256];
  int tid = threadIdx.x;
  emb[tid] = bf2f(embed[e*256 + tid]);
  __syncthreads();
  for (int c = tid; c < 768; c += 256){
    float s = bf2f(bih[c]);
    const uint32_t* wr = (const uint32_t*)(wih + (size_t)c*256);
    #pragma unroll 4
    for (int k2 = 0; k2 < 128; ++k2){
      float a, b; unp2(wr[k2], a, b);
      s += emb[k2*2]*a + emb[k2*2+1]*b;
    }
    GiE[(size_t)(dir*32 + e)*768 + c] = s;
  }
}

// -------------------------------------------------------------------------
// k_encoder: persistent bidirectional GRU over all 16 cyclic rolls.
// -------------------------------------------------------------------------
__global__ __launch_bounds__(512,2) void k_encoder(
    const int* __restrict__ lines, const float* __restrict__ GiE,
    const uint16_t* __restrict__ whh_f, const uint16_t* __restrict__ whh_b,
    const uint16_t* __restrict__ bhh_f, const uint16_t* __restrict__ bhh_b,
    uint16_t* __restrict__ Hmem /* [16][1024][512] */)
{
  int b = blockIdx.x;
  int dir = b >> 8; b &= 255;
  int r = b >> 4, n0 = (b & 15) << 6;
  const uint16_t* whh = dir ? whh_b : whh_f;
  const uint16_t* bhh = dir ? bhh_b : bhh_f;
  const float* gte = GiE + (size_t)dir * (32*768);

  __shared__ uint16_t hbuf[64*264];
  __shared__ int lid_s[64*16];

  int tid = threadIdx.x;
  for (int s = tid; s < 1024; s += 512) lid_s[s] = lines[(n0 + (s>>4))*16 + (s&15)];
  for (int s = tid; s < 8448; s += 512) ((uint32_t*)hbuf)[s] = 0u;

  int w = tid >> 6, lane = tid & 63, l15 = lane & 15, q = lane >> 4;
  int cw = w << 5;
  int nc[6];
  nc[0]=cw; nc[1]=cw+16; nc[2]=256+cw; nc[3]=256+cw+16; nc[4]=512+cw; nc[5]=512+cw+16;
  float bh[6];
  #pragma unroll
  for (int i=0;i<6;i++) bh[i] = bf2f(bhh[nc[i]+l15]);

  float hreg[4][2][4];
  #pragma unroll
  for (int a=0;a<4;a++)
    #pragma unroll
    for (int c=0;c<2;c++)
      #pragma unroll
      for (int e=0;e<4;e++) hreg[a][c][e]=0.f;

  __syncthreads();

  for (int j=0;j<16;++j){
    int jj = dir ? (15-j) : j;
    int pos = (r + jj) & 15;
    f32x4 acc[4][6];
    #pragma unroll
    for (int mt=0;mt<4;mt++)
      #pragma unroll
      for (int u=0;u<6;u++) acc[mt][u] = (f32x4){0.f,0.f,0.f,0.f};
    #pragma unroll
    for (int kb=0;kb<8;kb++){
      short8 af[4];
      #pragma unroll
      for (int mt=0;mt<4;mt++)
        af[mt] = *(const short8*)&hbuf[(mt*16+l15)*264 + kb*32 + q*8];
      #pragma unroll
      for (int u=0;u<6;u++){
        short8 bf = *(const short8*)&whh[(size_t)(nc[u]+l15)*256 + kb*32 + q*8];
        #pragma unroll
        for (int mt=0;mt<4;mt++) acc[mt][u] = MFMA(af[mt], bf, acc[mt][u]);
      }
    }
    __syncthreads();
    #pragma unroll
    for (int mt=0;mt<4;mt++){
      int lidv[4];
      #pragma unroll
      for (int e=0;e<4;e++) lidv[e] = lid_s[(mt*16 + q*4 + e)*16 + pos];
      float gv[4][6];
      #pragma unroll
      for (int e=0;e<4;e++)
        #pragma unroll
        for (int u=0;u<6;u++) gv[e][u] = gte[(size_t)lidv[e]*768 + nc[u] + l15];
      #pragma unroll
      for (int c=0;c<2;c++)
        #pragma unroll
        for (int e=0;e<4;e++){
          float ghr = acc[mt][c  ][e] + bh[c  ];
          float ghz = acc[mt][2+c][e] + bh[2+c];
          float ghn = acc[mt][4+c][e] + bh[4+c];
          float rr = sigm(gv[e][c] + ghr);
          float zz = sigm(gv[e][2+c] + ghz);
          float nn = tanhx(gv[e][4+c] + rr*ghn);
          float hn = (1.f-zz)*nn + zz*hreg[mt][c][e];
          hreg[mt][c][e] = hn;
          hbuf[(mt*16 + q*4 + e)*264 + cw + c*16 + l15] = f2bf(hn);
        }
    }
    __syncthreads();
  }
  for (int s = tid; s < 8192; s += 512){
    int row = s >> 7, cp = (s & 127) << 1;
    uint32_t v = *(uint32_t*)&hbuf[row*264 + cp];
    *(uint32_t*)&Hmem[(size_t)((r<<10) + n0 + row)*512 + (dir<<8) + cp] = v;
  }
}

// -------------------------------------------------------------------------
// k_gemm: C[M,N](bf16) = act( A[M,K] @ W[N,K]^T + bias + gather )
// flags: 1=relu, 2=bias, 4=gather (G[(gidx[row]*1024 + row%1024)*256 + col])
//        8=phasec-swizzled output layout (see k_phasec)
// -------------------------------------------------------------------------
__global__ __launch_bounds__(256,3) void k_gemm(
    const uint16_t* __restrict__ A, int lda,
    const uint16_t* __restrict__ W, int ldw, int woff,
    const uint16_t* __restrict__ bias,
    const int* __restrict__ gidx, const uint16_t* __restrict__ G,
    uint16_t* __restrict__ C, int ldc, int K, int flags)
{
  int n0 = blockIdx.x << 6, m0 = blockIdx.y << 7;
  int tid = threadIdx.x, w = tid>>6, lane = tid&63, l15 = lane&15, q = lane>>4;
  __shared__ uint16_t As[128*56];
  __shared__ uint16_t Ws[64*56];
  f32x4 acc[2][4];
  #pragma unroll
  for (int mt=0;mt<2;mt++)
    #pragma unroll
    for (int nt=0;nt<4;nt++) acc[mt][nt]=(f32x4){0.f,0.f,0.f,0.f};
  int nk = K >> 5;
  int arow0 = tid >> 2, ach = (tid & 3) << 3;
  for (int kb = 0; kb < nk; ++kb){
    int k0 = kb << 5;
    *(uint4*)&As[arow0*56 + ach]      = *(const uint4*)&A[(size_t)(m0+arow0)*lda + k0 + ach];
    *(uint4*)&As[(arow0+64)*56 + ach] = *(const uint4*)&A[(size_t)(m0+arow0+64)*lda + k0 + ach];
    *(uint4*)&Ws[arow0*56 + ach]      = *(const uint4*)&W[(size_t)(n0+arow0)*ldw + woff + k0 + ach];
    __syncthreads();
    short8 af[2], bfr[4];
    #pragma unroll
    for (int mt=0;mt<2;mt++) af[mt] = *(const short8*)&As[(w*32 + mt*16 + l15)*56 + q*8];
    #pragma unroll
    for (int nt=0;nt<4;nt++) bfr[nt] = *(const short8*)&Ws[(nt*16 + l15)*56 + q*8];
    #pragma unroll
    for (int mt=0;mt<2;mt++)
      #pragma unroll
      for (int nt=0;nt<4;nt++) acc[mt][nt] = MFMA(af[mt], bfr[nt], acc[mt][nt]);
    __syncthreads();
  }
  float bv[4] = {0.f,0.f,0.f,0.f};
  if (flags & 2){
    #pragma unroll
    for (int nt=0;nt<4;nt++) bv[nt] = bf2f(bias[n0 + nt*16 + l15]);
  }
  if (flags & 8){
    // phasec-swizzled store: pack 4 row-consecutive values into one 8B store
    #pragma unroll
    for (int mt=0;mt<2;mt++)
      #pragma unroll
      for (int nt=0;nt<4;nt++){
        int row0 = m0 + w*32 + mt*16 + q*4;       // rows row0..row0+3 (e fast)
        int t = row0 >> 10, n = row0 & 1023;
        int nblk = n >> 4;
        int colv = n0 + nt*16 + l15;
        int wp = (colv >> 5) & 7, u = (colv >> 8)*2 + ((colv >> 4) & 1);
        size_t base = ((((size_t)t*64 + nblk)*8 + wp)*16 + (size_t)l15)*96
                      + (size_t)q*24 + (size_t)u*4;
        union { uint16_t us[4]; uint2 v; } o;
        #pragma unroll
        for (int e=0;e<4;e++) o.us[e] = f2bf(acc[mt][nt][e] + bv[nt]);
        *(uint2*)&C[base] = o.v;
      }
  } else {
    #pragma unroll
    for (int mt=0;mt<2;mt++)
      #pragma unroll
      for (int e=0;e<4;e++){
        int row = m0 + w*32 + mt*16 + q*4 + e;
        size_t gb = 0;
        if (flags & 4) gb = ((size_t)gidx[row]*1024 + (size_t)(row & 1023))*256;
        #pragma unroll
        for (int nt=0;nt<4;nt++){
          int col = n0 + nt*16 + l15;
          float v = acc[mt][nt][e] + bv[nt];
          if (flags & 4) v += bf2f(G[gb + col]);
          if (flags & 1) v = fmaxf(v, 0.f);
          C[(size_t)row*ldc + col] = f2bf(v);
        }
      }
  }
}

// -------------------------------------------------------------------------
// k_phasec: sequential recurrence over a chunk of Tc steps.
// v5: kill the per-step weight re-stream (the dominant ~24k cy/step term).
//   * __launch_bounds__(512,1): allocator freed to ~256 VGPRs (512-thread
//     block keeps 2 waves/SIMD launchable, same occupancy as before).
//   * ALL hh-weights persistent in registers: bw[8][6] = 192 VGPRs, loaded
//     once in the prologue. Per-step global traffic is now just 3 Gi loads
//     + 4 h_s stores per thread (was 48 weight loads = 393KB/block/step
//     through the L1/L2 request path -> ~6k+ cy of memory-pipe occupancy).
//   * Gi for t+1 reloaded into the SAME gpk registers after elementwise
//     (anti-dependency pins the order; barrier drain covers the latency).
//   * double-buffered h tile, ONE __syncthreads per step (proven r3/r4).
// -------------------------------------------------------------------------
__global__ __launch_bounds__(512,1) void k_phasec(
    const uint16_t* __restrict__ Gi, const uint16_t* __restrict__ c_whh,
    const uint16_t* __restrict__ c_bhh, const uint16_t* __restrict__ hinit,
    uint16_t* __restrict__ hcur, uint16_t* __restrict__ h_s, int Tc)
{
  int bx = blockIdx.x;
  int n0 = bx << 4;
  int tid = threadIdx.x, w = tid>>6, lane = tid&63, l15 = lane&15, q = lane>>4;
  int cw = w<<5;
  int nc[6];
  nc[0]=cw; nc[1]=cw+16; nc[2]=256+cw; nc[3]=256+cw+16; nc[4]=512+cw; nc[5]=512+cw+16;

  __shared__ uint16_t hb[2][16*264];   // double-buffered h tile (padded rows)

  // swizzled Gi: offset(t) = (((t*64+bx)*8+w)*16+l15)*96 + q*24
  const size_t gstep = (size_t)64*8*16*96;             // = 786432 = 1024*768
  size_t goff0 = (((size_t)bx*8 + w)*16 + (size_t)l15)*96 + (size_t)q*24;

  // ---- prologue ----
  for (int s = tid; s < 2048; s += 512){
    int row = s >> 7, cp = (s&127) << 1;
    uint32_t v = *(const uint32_t*)&hinit[(size_t)(n0+row)*256 + cp];
    *(uint32_t*)&hb[0][row*264 + cp] = v;
  }
  float bh[6];
  #pragma unroll
  for (int i=0;i<6;i++) bh[i] = bf2f(c_bhh[nc[i]+l15]);
  float hreg[2][4];
  #pragma unroll
  for (int c=0;c<2;c++)
    #pragma unroll
    for (int e=0;e<4;e++)
      hreg[c][e] = bf2f(hinit[(size_t)(n0+q*4+e)*256 + cw + c*16 + l15]);
  // persistent weights: 8 k-blocks x 6 gate-columns, 192 VGPRs
  short8 bw[8][6];
  #pragma unroll
  for (int kb=0;kb<8;kb++)
    #pragma unroll
    for (int u=0;u<6;u++)
      bw[kb][u] = *(const short8*)&c_whh[(size_t)(nc[u]+l15)*256 + kb*32 + q*8];
  short8 gpk[3];
  {
    const uint16_t* gb = Gi + goff0;
    gpk[0] = *(const short8*)&gb[0];
    gpk[1] = *(const short8*)&gb[8];
    gpk[2] = *(const short8*)&gb[16];
  }
  __syncthreads();

  // unpack helper: value for (u,e) is element u*4+e of the packed 24
#define GV(u,e) bf2f((uint16_t)gpk[((u)*4+(e))>>3][((u)*4+(e))&7])

  int p = 0;
  for (int t=0;t<Tc;++t){
    // A: deferred h_s store of the previous tile (stable since last barrier)
    if (t > 0){
      #pragma unroll
      for (int i=0;i<4;i++){
        int s = tid + i*512;
        int row = s >> 7, cp = (s&127) << 1;
        *(uint32_t*)&h_s[(size_t)(((t-1)<<10) + n0 + row)*256 + cp] =
            *(const uint32_t*)&hb[p][row*264 + cp];
      }
    }
    // B: hh-matmul entirely from persistent registers + LDS
    f32x4 acc[6];
    #pragma unroll
    for (int u=0;u<6;u++) acc[u] = (f32x4){0.f,0.f,0.f,0.f};
    #pragma unroll
    for (int kb=0;kb<8;kb++){
      short8 af = *(const short8*)&hb[p][l15*264 + kb*32 + q*8];
      #pragma unroll
      for (int u=0;u<6;u++)
        acc[u] = MFMA(af, bw[kb][u], acc[u]);
    }
    // C: elementwise GRU update using gpk (loaded last step / prologue)
    #pragma unroll
    for (int c=0;c<2;c++)
      #pragma unroll
      for (int e=0;e<4;e++){
        int row = q*4+e;
        float ghr = acc[c  ][e]+bh[c  ];
        float ghz = acc[2+c][e]+bh[2+c];
        float ghn = acc[4+c][e]+bh[4+c];
        float rr = sigm(GV(c,e)+ghr), zz = sigm(GV(2+c,e)+ghz);
        float nn = tanhx(GV(4+c,e) + rr*ghn);
        float hn = (1.f-zz)*nn + zz*hreg[c][e];
        hreg[c][e] = hn;
        hb[p^1][row*264 + cw + c*16 + l15] = f2bf(hn);
      }
    // D: reload gpk for t+1 (same registers; anti-dep orders after C)
    {
      int tn = (t+1 < Tc) ? (t+1) : t;
      const uint16_t* gb = Gi + (size_t)tn*gstep + goff0;
      gpk[0] = *(const short8*)&gb[0];
      gpk[1] = *(const short8*)&gb[8];
      gpk[2] = *(const short8*)&gb[16];
    }
    // E: single per-step barrier; rotate
    __syncthreads();
    p ^= 1;
  }
#undef GV
  // epilogue: final tile -> hcur and h_s[Tc-1]
  for (int s = tid; s < 2048; s += 512){
    int row = s >> 7, cp = (s&127) << 1;
    uint32_t v = *(uint32_t*)&hb[p][row*264 + cp];
    *(uint32_t*)&hcur[(size_t)(n0+row)*256 + cp] = v;
    *(uint32_t*)&h_s[(size_t)(((Tc-1)<<10) + n0 + row)*256 + cp] = v;
  }
}

// -------------------------------------------------------------------------
// k_phased: heads + packing for one chunk. Output dtype chosen by flag.
// out row = 278: [a, p0, w, v, h(256), probs(16), pp0(2)]
// -------------------------------------------------------------------------
__global__ __launch_bounds__(256) void k_phased(
    const uint16_t* __restrict__ h_s /* chunk-local */,
    const uint16_t* __restrict__ w_actor, const uint16_t* __restrict__ b_actor,
    const uint16_t* __restrict__ w_critic, const uint16_t* __restrict__ b_critic,
    const int* __restrict__ actions /* global */, const int* __restrict__ active,
    const uint16_t* __restrict__ p0, const uint16_t* __restrict__ pp0,
    void* __restrict__ out, const int* __restrict__ flag, int row0g)
{
  int r0 = blockIdx.x << 6;          // chunk-local row base
  __shared__ uint16_t hb[64*264];
  __shared__ uint16_t wa[17*256];
  __shared__ float lv[64*18];
  int tid = threadIdx.x;
  for (int s = tid; s < 2048; s += 256){
    int row = s >> 5, ch = (s & 31) << 3;
    *(uint4*)&hb[row*264 + ch] = *(const uint4*)&h_s[(size_t)(r0+row)*256 + ch];
  }
  for (int s = tid; s < 512; s += 256)
    *(uint4*)&wa[s*8] = *(const uint4*)&w_actor[s*8];
  if (tid < 32) *(uint4*)&wa[4096 + tid*8] = *(const uint4*)&w_critic[tid*8];
  __syncthreads();
  int row = tid & 63, cg = tid >> 6;
  for (int c = cg; c < 17; c += 4){
    const uint32_t* hr = (const uint32_t*)&hb[row*264];
    const uint32_t* wr = (const uint32_t*)&wa[c*256];
    float s = 0.f;
    #pragma unroll 4
    for (int k2=0;k2<128;k2++){
      float a,b,c2,d; unp2(hr[k2],a,b); unp2(wr[k2],c2,d);
      s += a*c2 + b*d;
    }
    s += (c<16) ? bf2f(b_actor[c]) : bf2f(b_critic[0]);
    lv[row*18 + c] = s;
  }
  __syncthreads();
  if (tid < 64){
    float mx = -1e30f;
    #pragma unroll
    for (int c=0;c<16;c++) mx = fmaxf(mx, lv[tid*18+c]);
    float sum = 0.f;
    #pragma unroll
    for (int c=0;c<16;c++){ float ev = __expf(lv[tid*18+c]-mx); lv[tid*18+c]=ev; sum+=ev; }
    float inv = 1.f/sum;
    #pragma unroll
    for (int c=0;c<16;c++) lv[tid*18+c] *= inv;
  }
  __syncthreads();
  int isf = flag[0];
  float* outf = (float*)out;
  uint16_t* outb = (uint16_t*)out;
  for (int s = tid; s < 64*278; s += 256){
    int rw = s / 278, c = s - rw*278;
    int gr = row0g + r0 + rw;        // global row (t*1024+n)
    int n  = (r0 + rw) & 1023;
    float fv;
    if (c >= 4 && c < 260)        fv = bf2f(hb[rw*264 + (c-4)]);
    else if (c >= 260 && c < 276) fv = lv[rw*18 + (c-260)];
    else if (c == 0)              fv = (float)actions[gr];
    else if (c == 1)              fv = bf2f(p0[n]);
    else if (c == 2)              fv = (float)active[gr];
    else if (c == 3)              fv = lv[rw*18+16];
    else                          fv = bf2f(pp0[(n<<1) + (c-276)]);
    size_t off = (size_t)gr*278 + c;
    if (isf) outf[off] = fv;
    else     outb[off] = f2bf(fv);
  }
}

// -------------------------------------------------------------------------
extern "C" void kernel_launch(void* const* d_in, const int* in_sizes, int n_in,
                              void* d_out, int out_size, void* d_ws, size_t ws_size,
                              hipStream_t stream)
{
  (void)in_sizes; (void)n_in; (void)out_size;
  const int* active  = (const int*)d_in[1];
  const int* lines   = (const int*)d_in[2];
  const int* actions = (const int*)d_in[3];

  char* wsb = (char*)d_ws;
  size_t off = 0;
  auto aln  = [](size_t x){ return (x + 255) & ~(size_t)255; };
  auto carve = [&](size_t bytes)->char*{ char* p = wsb + off; off += aln(bytes); return p; };

  int*      flag   = (int*)     carve(256);
  float*    GiE    = (float*)   carve((size_t)2*32*768*4);
  uint16_t* Hmem   = (uint16_t*)carve((size_t)16*1024*512*2);
  uint16_t* Rpart  = (uint16_t*)carve((size_t)16384*256*2);
  uint16_t* hcur   = (uint16_t*)carve((size_t)1024*256*2);
  uint16_t* condbf = (uint16_t*)carve((size_t)262144*64*2);

  // bf16 copies of all float inputs
  struct Item { int idx; int n; };
  const Item items[26] = {
    {8,196608},{9,196608},{10,768},{11,768},{12,196608},{13,196608},{14,768},{15,768},
    {16,147456},{17,256},{18,65536},{19,256},{20,65536},{21,256},
    {22,196608},{23,196608},{24,768},{25,768},
    {26,256},{27,1},{28,4096},{29,16},{5,1024},{6,2048},{7,8192},{4,262144}};
  uint16_t* bf[30] = {};
  CvtTab tab;
  for (int i=0;i<26;i++){
    uint16_t* d = (uint16_t*)carve((size_t)items[i].n*2);
    bf[items[i].idx] = d;
    tab.e[i].src = d_in[items[i].idx];
    tab.e[i].dst = d;
    tab.e[i].n   = items[i].n;
    tab.e[i].pad = 0;
  }

  // pick chunk size from remaining workspace
  size_t fixedBytes = off;
  int Tc = 4;
  const int cands[7] = {256,128,64,32,16,8,4};
  for (int i=0;i<7;i++){
    int c = cands[i];
    size_t need = fixedBytes + 2*aln((size_t)c*1024*256*2) + aln((size_t)c*1024*768*2);
    if (need <= ws_size){ Tc = c; break; }
  }
  uint16_t* Xa  = (uint16_t*)carve((size_t)Tc*1024*256*2);
  uint16_t* Xb  = (uint16_t*)carve((size_t)Tc*1024*256*2);
  uint16_t* Gic = (uint16_t*)carve((size_t)Tc*1024*768*2);

  // 0) dtype detect + normalize to internal bf16
  k_detect<<<1,256,0,stream>>>((const uint16_t*)d_in[7], flag);
  k_convert_small<<<26,1024,0,stream>>>(tab, flag);
  k_convert_big<<<8192,256,0,stream>>>(d_in[0], condbf, 2097152, flag);

  // 1) input-side GRU tables
  k_tables<<<64,256,0,stream>>>(bf[7], bf[8], bf[10], bf[12], bf[14], GiE);
  // 2) bidirectional encoder -> Hmem [16][1024][512]
  k_encoder<<<512,512,0,stream>>>(lines, GiE, bf[9], bf[13], bf[11], bf[15], Hmem);
  // 3) Rpart = Hmem @ f_w0[:,64:].T
  k_gemm<<<dim3(4,128),256,0,stream>>>(Hmem,512, bf[16],576,64, nullptr, nullptr,nullptr,
                                       Rpart,256, 512, 0);
  // chunked T loop
  for (int t0 = 0; t0 < 256; t0 += Tc){
    const uint16_t* condc = condbf + (size_t)t0*1024*64;
    const int* activec = active + t0*1024;
    // X0 = relu(cond @ f_w0[:,:64].T + Rpart[active] + b0)
    k_gemm<<<dim3(4,Tc*8),256,0,stream>>>(condc,64, bf[16],576,0, bf[17], activec, Rpart,
                                          Xa,256, 64, 7);
    // X1 = relu(X0 @ f_w1.T + b1)
    k_gemm<<<dim3(4,Tc*8),256,0,stream>>>(Xa,256, bf[18],256,0, bf[19], nullptr,nullptr,
                                          Xb,256, 256, 3);
    // X2 = relu(X1 @ f_w2.T + b2)
    k_gemm<<<dim3(4,Tc*8),256,0,stream>>>(Xb,256, bf[20],256,0, bf[21], nullptr,nullptr,
                                          Xa,256, 256, 3);
    // Gi = X2 @ c_wih.T + c_bih   (flag 8: phasec-swizzled layout)
    k_gemm<<<dim3(12,Tc*8),256,0,stream>>>(Xa,256, bf[22],256,0, bf[24], nullptr,nullptr,
                                           Gic,768, 256, 10);
    // recurrence chunk (h_s into Xb; X1 is dead by now)
    k_phasec<<<64,512,0,stream>>>(Gic, bf[23], bf[25], (t0==0 ? bf[4] : hcur), hcur, Xb, Tc);
    // heads + packing
    k_phased<<<Tc*16,256,0,stream>>>(Xb, bf[28], bf[29], bf[26], bf[27],
                                     actions, active, bf[5], bf[6],
                                     d_out, flag, t0*1024);
  }
}